// Round 3
// baseline (3160.833 us; speedup 1.0000x reference)
//
#include <hip/hip_runtime.h>
#include <hip/hip_bf16.h>
#include <math.h>

// Problem constants (B=16, T=2048, D=64, K=8192)
#define N_ROWS 32768
#define KCODES 8192
#define DDIM 64

typedef __attribute__((ext_vector_type(8))) short bf16x8;
typedef __attribute__((ext_vector_type(4))) float f32x4;

// ===================== FAST PATH =====================
// ws layout (bytes):
//   O_XBF   = 0        : x_bf   N*64 bf16            (4 MB)
//   O_QPERM = 4 MB     : codebook in MFMA-B-frag order (1 MB)
//   O_X2    = 5242880  : x2  N f32
//   O_E2    = 5373952  : e2  K f32
//   O_E2MAX = 5406720  : 1 f32 (atomicMax int-bits; 0xAA poison is negative -> safe)
//   O_CNT   = 5406736  : per-row candidate counts, N i32
//   O_SLOTS = 5537808  : candidates N*CAP i32 (8 MB)
#define CAP 64
#define O_XBF   0
#define O_QPERM 4194304UL
#define O_X2    5242880UL
#define O_E2    5373952UL
#define O_E2MAX 5406720UL
#define O_CNT   5406736UL
#define O_SLOTS 5537808UL
#define WS_NEEDED (O_SLOTS + (size_t)N_ROWS * CAP * 4)

__device__ __forceinline__ unsigned short f2bf(float f) {
    __hip_bfloat16 h = __float2bfloat16(f);  // RNE
    union { __hip_bfloat16 b; unsigned short u; } u;
    u.b = h;
    return u.u;
}

// prep: bf16 convert (x -> xbf rows; cb -> Qperm fragment-order) + numpy-pairwise
// sumsq + e2max + zero counters
__global__ __launch_bounds__(256) void prep_kernel(const float* __restrict__ x,
                                                   const float* __restrict__ cb,
                                                   unsigned short* __restrict__ xbf,
                                                   uint4* __restrict__ qperm,
                                                   float* __restrict__ x2,
                                                   float* __restrict__ e2,
                                                   int* __restrict__ e2max_bits,
                                                   int* __restrict__ cnt) {
#pragma clang fp contract(off)
    int t = blockIdx.x * 256 + threadIdx.x;  // exactly N_ROWS + KCODES threads
    bool iscb = (t >= N_ROWS);
    int r = iscb ? (t - N_ROWS) : t;
    const float* src = iscb ? (cb + (size_t)r * DDIM) : (x + (size_t)r * DDIM);
    if (!iscb) cnt[r] = 0;

    // build bf16 row as 8 x 16B chunks
    uint4 ch[8];
#pragma unroll
    for (int h = 0; h < 8; ++h) {
        float4 v0 = ((const float4*)src)[h * 2];
        float4 v1 = ((const float4*)src)[h * 2 + 1];
        ushort4 a, b;
        a.x = f2bf(v0.x); a.y = f2bf(v0.y); a.z = f2bf(v0.z); a.w = f2bf(v0.w);
        b.x = f2bf(v1.x); b.y = f2bf(v1.y); b.z = f2bf(v1.z); b.w = f2bf(v1.w);
        union { struct { ushort4 lo, hi; } s; uint4 u; } pk;
        pk.s.lo = a; pk.s.hi = b;
        ch[h] = pk.u;
    }
    if (!iscb) {
        uint4* dst = (uint4*)(xbf + (size_t)r * DDIM);
#pragma unroll
        for (int h = 0; h < 8; ++h) dst[h] = ch[h];
    } else {
        // frag-order: slot = ((c>>4)*2 + (h>>2))*64 + (h&3)*16 + (c&15)
        int g = r >> 4, l15 = r & 15;
#pragma unroll
        for (int h = 0; h < 8; ++h) {
            int slot = (g * 2 + (h >> 2)) * 64 + (h & 3) * 16 + l15;
            qperm[slot] = ch[h];
        }
    }

    // numpy pairwise sumsq (8 accumulators, contraction off)
    float acc[8];
#pragma unroll
    for (int j = 0; j < 8; ++j) { float v = src[j]; acc[j] = v * v; }
#pragma unroll
    for (int i = 8; i < 64; i += 8)
#pragma unroll
        for (int j = 0; j < 8; ++j) { float v = src[i + j]; acc[j] = acc[j] + v * v; }
    float s = ((acc[0] + acc[1]) + (acc[2] + acc[3])) + ((acc[4] + acc[5]) + (acc[6] + acc[7]));
    if (!iscb) {
        x2[r] = s;
    } else {
        e2[r] = s;
        atomicMax(e2max_bits, __float_as_int(s));
    }
}

// screen: LDS-free, barrier-free bf16 MFMA screen with immediate-consume scores.
// grid (512 blocks x 256 thr): block = 64 rows; wave w = K-split w (2048 codes, 128 tiles).
__global__ __launch_bounds__(256) void screen_kernel(const unsigned short* __restrict__ xbf,
                                                     const uint4* __restrict__ qperm,
                                                     const float* __restrict__ x2g,
                                                     const float* __restrict__ e2g,
                                                     const int* __restrict__ e2max_bits,
                                                     int* __restrict__ cnt,
                                                     int* __restrict__ slots) {
    const int tid = threadIdx.x;
    const int split = tid >> 6;
    const int lane = tid & 63;
    const int l15 = lane & 15;
    const int quad = lane >> 4;
    const int row0 = blockIdx.x * 64;
    const int code0 = split * 2048;

    // A fragments: 4 row-tiles x 2 k-steps, resident all kernel (32 VGPRs)
    bf16x8 afrag[4][2];
#pragma unroll
    for (int rt = 0; rt < 4; ++rt)
#pragma unroll
        for (int s = 0; s < 2; ++s)
            afrag[rt][s] = *(const bf16x8*)(xbf + (size_t)(row0 + rt * 16 + l15) * DDIM +
                                            s * 32 + quad * 8);

    // wave-uniform margin from x2max over the wave's 64 rows
    float xm = x2g[row0 + lane];
#pragma unroll
    for (int m = 1; m < 64; m <<= 1) xm = fmaxf(xm, __shfl_xor(xm, m, 64));
    const float e2max = __int_as_float(*e2max_bits);
    const float M = 0.032f * sqrtf(xm * e2max) + 0.03f;

    // running thresholds thr = runmin + M per (rt, reg)
    float thr[4][4];
#pragma unroll
    for (int rt = 0; rt < 4; ++rt)
#pragma unroll
        for (int reg = 0; reg < 4; ++reg) thr[rt][reg] = 3.0e38f;

    const uint4* Qb = qperm + (size_t)(split * 128) * 2 * 64;

    // ping-pong prefetch buffers; logical sequence L(i)= i<2 ? i : i-2
    // (tiles 0,1 min-only warmup, then 0..127 with collection)
    bf16x8 bb0[2], bb1[2];
    float ee2[2];
#pragma unroll
    for (int i = 0; i < 2; ++i) {
        const uint4* p = Qb + (size_t)(i * 2) * 64 + lane;
        bb0[i] = *(const bf16x8*)p;
        bb1[i] = *(const bf16x8*)(p + 64);
        ee2[i] = e2g[code0 + i * 16 + l15];
    }

#pragma unroll 2
    for (int i = 0; i < 130; ++i) {
        const int buf = i & 1;
        const int t = (i < 2) ? i : (i - 2);
        const bool collect = (i >= 2);
        const bf16x8 B0 = bb0[buf];
        const bf16x8 B1 = bb1[buf];
        const float e2v = ee2[buf];

        // prefetch tile i (consumed at iteration i+2) into same-parity buffer
        if (i < 128) {
            const uint4* p = Qb + (size_t)(i * 2) * 64 + lane;
            bb0[buf] = *(const bf16x8*)p;
            bb1[buf] = *(const bf16x8*)(p + 64);
            ee2[buf] = e2g[code0 + i * 16 + l15];
        }

        const int myCode = code0 + t * 16 + l15;
        const f32x4 z = {0.0f, 0.0f, 0.0f, 0.0f};
#pragma unroll
        for (int rt = 0; rt < 4; ++rt) {
            f32x4 acc = __builtin_amdgcn_mfma_f32_16x16x32_bf16(afrag[rt][0], B0, z, 0, 0, 0);
            acc = __builtin_amdgcn_mfma_f32_16x16x32_bf16(afrag[rt][1], B1, acc, 0, 0, 0);
#pragma unroll
            for (int reg = 0; reg < 4; ++reg) {
                float sc = fmaf(-2.0f, acc[reg], e2v);  // e2 - 2*xe (x2 is row-const)
                if (collect && (sc <= thr[rt][reg])) {
                    int row = row0 + rt * 16 + quad * 4 + reg;
                    int pos = atomicAdd(&cnt[row], 1);
                    if (pos < CAP) slots[(size_t)row * CAP + pos] = myCode;
                }
                thr[rt][reg] = fminf(thr[rt][reg], sc + M);
            }
        }

        // periodic cross-lane threshold tightening (lanes sharing a row = same quad, all l15)
        if (i == 1 || i == 5 || i == 9 || i == 17 || i == 33 || i == 65) {
#pragma unroll
            for (int rt = 0; rt < 4; ++rt)
#pragma unroll
                for (int reg = 0; reg < 4; ++reg) {
                    float v = thr[rt][reg];
                    v = fminf(v, __shfl_xor(v, 1, 64));
                    v = fminf(v, __shfl_xor(v, 2, 64));
                    v = fminf(v, __shfl_xor(v, 4, 64));
                    v = fminf(v, __shfl_xor(v, 8, 64));
                    thr[rt][reg] = v;
                }
        }
    }
}

// finalize: exact fp32 re-evaluation of candidates (numpy-order), outputs
__global__ __launch_bounds__(256) void finalize2_kernel(const float* __restrict__ x,
                                                        const float* __restrict__ cb,
                                                        const float* __restrict__ x2,
                                                        const float* __restrict__ e2,
                                                        const int* __restrict__ cnt,
                                                        const int* __restrict__ slots,
                                                        float* __restrict__ out) {
    __shared__ float bvs[256];
    __shared__ int bis[256];
    int t = blockIdx.x * 256 + threadIdx.x;  // N_ROWS*4 threads
    int r = t >> 2, j = t & 3;
    const int tid = threadIdx.x;

    float xr[64];
#pragma unroll
    for (int q = 0; q < 16; ++q) {
        float4 v = ((const float4*)(x + (size_t)r * DDIM))[q];
        xr[q * 4 + 0] = v.x; xr[q * 4 + 1] = v.y; xr[q * 4 + 2] = v.z; xr[q * 4 + 3] = v.w;
    }
    float x2v = x2[r];

    float bv = 3.0e38f;
    int bi = 0x7fffffff;
    int c = cnt[r];
    if (c > 0 && c <= CAP) {
        for (int i = j; i < c; i += 4) {
            int code = slots[(size_t)r * CAP + i];
            float xe = 0.0f;
            const float4* e4 = (const float4*)(cb + (size_t)code * DDIM);
#pragma unroll
            for (int q = 0; q < 16; ++q) {
                float4 ev = e4[q];
                xe = fmaf(xr[q * 4 + 0], ev.x, xe);
                xe = fmaf(xr[q * 4 + 1], ev.y, xe);
                xe = fmaf(xr[q * 4 + 2], ev.z, xe);
                xe = fmaf(xr[q * 4 + 3], ev.w, xe);
            }
            float ts = x2v + e2[code];
            float dist = fmaf(-2.0f, xe, ts);
            if (dist < bv || (dist == bv && code < bi)) { bv = dist; bi = code; }
        }
    } else {
        // backstop: full scan (covers c==0 / overflow)
        for (int code = j; code < KCODES; code += 4) {
            float xe = 0.0f;
            const float4* e4 = (const float4*)(cb + (size_t)code * DDIM);
#pragma unroll
            for (int q = 0; q < 16; ++q) {
                float4 ev = e4[q];
                xe = fmaf(xr[q * 4 + 0], ev.x, xe);
                xe = fmaf(xr[q * 4 + 1], ev.y, xe);
                xe = fmaf(xr[q * 4 + 2], ev.z, xe);
                xe = fmaf(xr[q * 4 + 3], ev.w, xe);
            }
            float ts = x2v + e2[code];
            float dist = fmaf(-2.0f, xe, ts);
            if (dist < bv || (dist == bv && code < bi)) { bv = dist; bi = code; }
        }
    }
    bvs[tid] = bv;
    bis[tid] = bi;
    __syncthreads();
    int base = tid & ~3;
    if (j == 0) {
#pragma unroll
        for (int jj = 1; jj < 4; ++jj) {
            float v = bvs[base + jj];
            int ii = bis[base + jj];
            if (v < bv || (v == bv && ii < bi)) { bv = v; bi = ii; }
        }
        bis[base] = bi;
    }
    __syncthreads();
    int best = bis[base];

    const float4* qs = (const float4*)(cb + (size_t)best * DDIM);
    float4* os = (float4*)(out + (size_t)r * DDIM);
#pragma unroll
    for (int i = 0; i < 4; ++i) {
        float4 qv = qs[j * 4 + i];
        float xv0 = xr[(j * 4 + i) * 4 + 0], xv1 = xr[(j * 4 + i) * 4 + 1];
        float xv2 = xr[(j * 4 + i) * 4 + 2], xv3 = xr[(j * 4 + i) * 4 + 3];
        float4 ov;
        ov.x = xv0 + (qv.x - xv0);
        ov.y = xv1 + (qv.y - xv1);
        ov.z = xv2 + (qv.z - xv2);
        ov.w = xv3 + (qv.w - xv3);
        os[j * 4 + i] = ov;
    }
    if (j == 0) out[(size_t)N_ROWS * DDIM + r] = (float)best;
}

// ===================== FALLBACK PATH (round-1, correct at 493 us) =====================
#define SPLITK 4
#define KPER (KCODES / SPLITK)
#define TM 128
#define TKT 128
#define NTILES (KPER / TKT)
#define LDSX 132
#define LDSE 132

__global__ __launch_bounds__(256) void sumsq_kernel(const float* __restrict__ x,
                                                    const float* __restrict__ cb,
                                                    float* __restrict__ ws) {
#pragma clang fp contract(off)
    int t = blockIdx.x * 256 + threadIdx.x;
    const float* src;
    float* dst;
    if (t < KCODES) { src = cb + (size_t)t * DDIM; dst = ws + t; }
    else { int r = t - KCODES; src = x + (size_t)r * DDIM; dst = ws + KCODES + r; }
    float acc[8];
#pragma unroll
    for (int j = 0; j < 8; ++j) { float v = src[j]; acc[j] = v * v; }
#pragma unroll
    for (int i = 8; i < 64; i += 8)
#pragma unroll
        for (int j = 0; j < 8; ++j) { float v = src[i + j]; acc[j] = acc[j] + v * v; }
    *dst = ((acc[0] + acc[1]) + (acc[2] + acc[3])) + ((acc[4] + acc[5]) + (acc[6] + acc[7]));
}

__global__ __launch_bounds__(256) void dist_argmin_kernel(const float* __restrict__ x,
                                                          const float* __restrict__ cb,
                                                          const float* __restrict__ e2g,
                                                          const float* __restrict__ x2g,
                                                          float2* __restrict__ partial) {
    __shared__ float smem[DDIM * LDSX + DDIM * LDSE];
    float* Xs = smem;
    float* Es = smem + DDIM * LDSX;
    const int tid = threadIdx.x;
    const int row0 = blockIdx.x * TM;
    const int code0 = blockIdx.y * KPER;
    const int tr = tid >> 4, tc = tid & 15;
    for (int i = tid; i < TM * 16; i += 256) {
        int r = i >> 4, q = i & 15;
        float4 v = ((const float4*)(x + (size_t)(row0 + r) * DDIM))[q];
        Xs[(4 * q + 0) * LDSX + r] = v.x; Xs[(4 * q + 1) * LDSX + r] = v.y;
        Xs[(4 * q + 2) * LDSX + r] = v.z; Xs[(4 * q + 3) * LDSX + r] = v.w;
    }
    float x2v[8];
#pragma unroll
    for (int j = 0; j < 8; ++j) x2v[j] = x2g[row0 + tr * 8 + j];
    float bestV[8]; int bestI[8];
#pragma unroll
    for (int j = 0; j < 8; ++j) { bestV[j] = 3.0e38f; bestI[j] = 0; }
    for (int t = 0; t < NTILES; ++t) {
        __syncthreads();
        const int cbase = code0 + t * TKT;
        for (int i = tid; i < TKT * 16; i += 256) {
            int c = i >> 4, q = i & 15;
            float4 v = ((const float4*)(cb + (size_t)(cbase + c) * DDIM))[q];
            Es[(4 * q + 0) * LDSE + c] = v.x; Es[(4 * q + 1) * LDSE + c] = v.y;
            Es[(4 * q + 2) * LDSE + c] = v.z; Es[(4 * q + 3) * LDSE + c] = v.w;
        }
        __syncthreads();
        float acc[8][8];
#pragma unroll
        for (int a = 0; a < 8; ++a)
#pragma unroll
            for (int b = 0; b < 8; ++b) acc[a][b] = 0.0f;
#pragma unroll 4
        for (int d = 0; d < DDIM; ++d) {
            float xv[8], ev[8];
            float4 xa = *(const float4*)&Xs[d * LDSX + tr * 8];
            float4 xb = *(const float4*)&Xs[d * LDSX + tr * 8 + 4];
            float4 ea = *(const float4*)&Es[d * LDSE + tc * 8];
            float4 eb = *(const float4*)&Es[d * LDSE + tc * 8 + 4];
            xv[0] = xa.x; xv[1] = xa.y; xv[2] = xa.z; xv[3] = xa.w;
            xv[4] = xb.x; xv[5] = xb.y; xv[6] = xb.z; xv[7] = xb.w;
            ev[0] = ea.x; ev[1] = ea.y; ev[2] = ea.z; ev[3] = ea.w;
            ev[4] = eb.x; ev[5] = eb.y; ev[6] = eb.z; ev[7] = eb.w;
#pragma unroll
            for (int a = 0; a < 8; ++a)
#pragma unroll
                for (int b = 0; b < 8; ++b) acc[a][b] = fmaf(xv[a], ev[b], acc[a][b]);
        }
#pragma unroll
        for (int b = 0; b < 8; ++b) {
            int ci = cbase + tc * 8 + b;
            float e2 = e2g[ci];
#pragma unroll
            for (int a = 0; a < 8; ++a) {
                float ts = x2v[a] + e2;
                float dist = fmaf(-2.0f, acc[a][b], ts);
                if (dist < bestV[a]) { bestV[a] = dist; bestI[a] = ci; }
            }
        }
    }
    __syncthreads();
    float* redV = Es;
    int* redI = (int*)(Es + TM * 16);
#pragma unroll
    for (int a = 0; a < 8; ++a) {
        redV[(tr * 8 + a) * 16 + tc] = bestV[a];
        redI[(tr * 8 + a) * 16 + tc] = bestI[a];
    }
    __syncthreads();
    if (tid < TM) {
        float bv = redV[tid * 16];
        int bi = redI[tid * 16];
#pragma unroll
        for (int c = 1; c < 16; ++c) {
            float v = redV[tid * 16 + c];
            int ii = redI[tid * 16 + c];
            if (v < bv || (v == bv && ii < bi)) { bv = v; bi = ii; }
        }
        partial[(size_t)(row0 + tid) * SPLITK + blockIdx.y] = make_float2(bv, __int_as_float(bi));
    }
}

__global__ __launch_bounds__(256) void finalize_kernel(const float2* __restrict__ partial,
                                                       const float* __restrict__ x,
                                                       const float* __restrict__ cb,
                                                       float* __restrict__ out) {
    int t = blockIdx.x * 256 + threadIdx.x;
    int r = t >> 2, j = t & 3;
    float2 p = partial[(size_t)r * SPLITK];
    float bv = p.x;
    int bi = __float_as_int(p.y);
#pragma unroll
    for (int k = 1; k < SPLITK; ++k) {
        float2 q = partial[(size_t)r * SPLITK + k];
        int qi = __float_as_int(q.y);
        if (q.x < bv || (q.x == bv && qi < bi)) { bv = q.x; bi = qi; }
    }
    const float4* xs = (const float4*)(x + (size_t)r * DDIM);
    const float4* qs = (const float4*)(cb + (size_t)bi * DDIM);
    float4* os = (float4*)(out + (size_t)r * DDIM);
#pragma unroll
    for (int i = 0; i < 4; ++i) {
        float4 xv = xs[j * 4 + i];
        float4 qv = qs[j * 4 + i];
        float4 ov;
        ov.x = xv.x + (qv.x - xv.x); ov.y = xv.y + (qv.y - xv.y);
        ov.z = xv.z + (qv.z - xv.z); ov.w = xv.w + (qv.w - xv.w);
        os[j * 4 + i] = ov;
    }
    if (j == 0) out[(size_t)N_ROWS * DDIM + r] = (float)bi;
}

// ===================== LAUNCH =====================
extern "C" void kernel_launch(void* const* d_in, const int* in_sizes, int n_in,
                              void* d_out, int out_size, void* d_ws, size_t ws_size,
                              hipStream_t stream) {
    const float* x = (const float*)d_in[0];
    const float* cb = (const float*)d_in[1];
    float* out = (float*)d_out;

    if (ws_size >= WS_NEEDED) {
        unsigned char* ws = (unsigned char*)d_ws;
        unsigned short* xbf = (unsigned short*)(ws + O_XBF);
        uint4* qperm = (uint4*)(ws + O_QPERM);
        float* x2 = (float*)(ws + O_X2);
        float* e2 = (float*)(ws + O_E2);
        int* e2max_bits = (int*)(ws + O_E2MAX);
        int* cnt = (int*)(ws + O_CNT);
        int* slots = (int*)(ws + O_SLOTS);

        prep_kernel<<<(N_ROWS + KCODES) / 256, 256, 0, stream>>>(x, cb, xbf, qperm, x2, e2,
                                                                 e2max_bits, cnt);
        screen_kernel<<<N_ROWS / 64, 256, 0, stream>>>(xbf, qperm, x2, e2, e2max_bits, cnt,
                                                       slots);
        finalize2_kernel<<<(N_ROWS * 4) / 256, 256, 0, stream>>>(x, cb, x2, e2, cnt, slots, out);
    } else {
        float* ws = (float*)d_ws;
        float* e2 = ws;
        float* x2 = ws + KCODES;
        float2* partial = (float2*)(ws + KCODES + N_ROWS);
        sumsq_kernel<<<(KCODES + N_ROWS) / 256, 256, 0, stream>>>(x, cb, ws);
        dim3 grid(N_ROWS / TM, SPLITK);
        dist_argmin_kernel<<<grid, 256, 0, stream>>>(x, cb, e2, x2, partial);
        finalize_kernel<<<(N_ROWS * 4) / 256, 256, 0, stream>>>(partial, x, cb, out);
    }
}

// Round 4
// 220.353 us; speedup vs baseline: 14.3444x; 14.3444x over previous
//
#include <hip/hip_runtime.h>
#include <hip/hip_bf16.h>
#include <math.h>

// Problem constants (B=16, T=2048, D=64, K=8192)
#define N_ROWS 32768
#define KCODES 8192
#define DDIM 64

typedef __attribute__((ext_vector_type(8))) short bf16x8;
typedef __attribute__((ext_vector_type(4))) float f32x4;

// ===================== FAST PATH =====================
// ws layout (bytes):
//   O_XBF   = 0        : x_bf   N*64 bf16            (4 MB)
//   O_QPERM = 4 MB     : codebook in MFMA-B-frag order (1 MB)
//   O_X2    = 5242880  : x2  N f32
//   O_E2    = 5373952  : e2  K f32
//   O_E2MAX = 5406720  : 1 f32 (atomicMax int-bits; 0xAA poison is negative -> safe)
//   O_CNT   = 5406736  : per-row candidate counts, N i32
//   O_SLOTS = 5537808  : candidates N*CAP i32 (2 MB)
#define CAP 16
#define O_XBF   0
#define O_QPERM 4194304UL
#define O_X2    5242880UL
#define O_E2    5373952UL
#define O_E2MAX 5406720UL
#define O_CNT   5406736UL
#define O_SLOTS 5537808UL
#define WS_NEEDED (O_SLOTS + (size_t)N_ROWS * CAP * 4)

__device__ __forceinline__ unsigned short f2bf(float f) {
    __hip_bfloat16 h = __float2bfloat16(f);  // RNE
    union { __hip_bfloat16 b; unsigned short u; } u;
    u.b = h;
    return u.u;
}

// prep: bf16 convert (x -> xbf rows; cb -> Qperm fragment-order) + numpy-pairwise
// sumsq + e2max + zero counters
__global__ __launch_bounds__(256) void prep_kernel(const float* __restrict__ x,
                                                   const float* __restrict__ cb,
                                                   unsigned short* __restrict__ xbf,
                                                   uint4* __restrict__ qperm,
                                                   float* __restrict__ x2,
                                                   float* __restrict__ e2,
                                                   int* __restrict__ e2max_bits,
                                                   int* __restrict__ cnt) {
#pragma clang fp contract(off)
    int t = blockIdx.x * 256 + threadIdx.x;  // exactly N_ROWS + KCODES threads
    bool iscb = (t >= N_ROWS);
    int r = iscb ? (t - N_ROWS) : t;
    const float* src = iscb ? (cb + (size_t)r * DDIM) : (x + (size_t)r * DDIM);
    if (!iscb) cnt[r] = 0;

    // build bf16 row as 8 x 16B chunks
    uint4 ch[8];
#pragma unroll
    for (int h = 0; h < 8; ++h) {
        float4 v0 = ((const float4*)src)[h * 2];
        float4 v1 = ((const float4*)src)[h * 2 + 1];
        ushort4 a, b;
        a.x = f2bf(v0.x); a.y = f2bf(v0.y); a.z = f2bf(v0.z); a.w = f2bf(v0.w);
        b.x = f2bf(v1.x); b.y = f2bf(v1.y); b.z = f2bf(v1.z); b.w = f2bf(v1.w);
        union { struct { ushort4 lo, hi; } s; uint4 u; } pk;
        pk.s.lo = a; pk.s.hi = b;
        ch[h] = pk.u;
    }
    if (!iscb) {
        uint4* dst = (uint4*)(xbf + (size_t)r * DDIM);
#pragma unroll
        for (int h = 0; h < 8; ++h) dst[h] = ch[h];
    } else {
        // frag-order: slot = ((c>>4)*2 + (h>>2))*64 + (h&3)*16 + (c&15)
        int g = r >> 4, l15 = r & 15;
#pragma unroll
        for (int h = 0; h < 8; ++h) {
            int slot = (g * 2 + (h >> 2)) * 64 + (h & 3) * 16 + l15;
            qperm[slot] = ch[h];
        }
    }

    // numpy pairwise sumsq (8 accumulators, contraction off)
    float acc[8];
#pragma unroll
    for (int j = 0; j < 8; ++j) { float v = src[j]; acc[j] = v * v; }
#pragma unroll
    for (int i = 8; i < 64; i += 8)
#pragma unroll
        for (int j = 0; j < 8; ++j) { float v = src[i + j]; acc[j] = acc[j] + v * v; }
    float s = ((acc[0] + acc[1]) + (acc[2] + acc[3])) + ((acc[4] + acc[5]) + (acc[6] + acc[7]));
    if (!iscb) {
        x2[r] = s;
    } else {
        e2[r] = s;
        atomicMax(e2max_bits, __float_as_int(s));
    }
}

// screen: fused two-pass. Pass A: bf16 MFMA min-only (no branches/atomics).
// LDS combine of the 4 K-splits -> global approx min per row. Pass B: rerun GEMM,
// collect codes with sc <= global_min + M (rare -> atomics cheap).
// grid 512 blocks x 256 thr: block = 64 rows; wave w = K-split w (2048 codes, 128 tiles).
__global__ __launch_bounds__(256) void screen_kernel(const unsigned short* __restrict__ xbf,
                                                     const uint4* __restrict__ qperm,
                                                     const float* __restrict__ x2g,
                                                     const float* __restrict__ e2g,
                                                     const int* __restrict__ e2max_bits,
                                                     int* __restrict__ cnt,
                                                     int* __restrict__ slots) {
    __shared__ float sm[4 * 64];

    const int tid = threadIdx.x;
    const int split = tid >> 6;
    const int lane = tid & 63;
    const int l15 = lane & 15;
    const int quad = lane >> 4;
    const int row0 = blockIdx.x * 64;
    const int code0 = split * 2048;

    // A fragments: 4 row-tiles x 2 k-steps, resident all kernel (32 VGPRs)
    bf16x8 afrag[4][2];
#pragma unroll
    for (int rt = 0; rt < 4; ++rt)
#pragma unroll
        for (int s = 0; s < 2; ++s)
            afrag[rt][s] = *(const bf16x8*)(xbf + (size_t)(row0 + rt * 16 + l15) * DDIM +
                                            s * 32 + quad * 8);

    const uint4* Qb = qperm + (size_t)split * 128 * 128;  // 128 tiles x 128 uint4

    // ---------- Pass A: min-only ----------
    bf16x8 bb0[2], bb1[2];
    float ee2[2];
#pragma unroll
    for (int i = 0; i < 2; ++i) {
        const uint4* p = Qb + i * 128 + lane;
        bb0[i] = *(const bf16x8*)p;
        bb1[i] = *(const bf16x8*)(p + 64);
        ee2[i] = e2g[code0 + i * 16 + l15];
    }
    float runmin[4][4];
#pragma unroll
    for (int rt = 0; rt < 4; ++rt)
#pragma unroll
        for (int reg = 0; reg < 4; ++reg) runmin[rt][reg] = 3.0e38f;

#pragma unroll 2
    for (int i = 0; i < 128; ++i) {
        const int buf = i & 1;
        const bf16x8 B0 = bb0[buf];
        const bf16x8 B1 = bb1[buf];
        const float e2v = ee2[buf];
        if (i < 126) {
            const uint4* p = Qb + (i + 2) * 128 + lane;
            bb0[buf] = *(const bf16x8*)p;
            bb1[buf] = *(const bf16x8*)(p + 64);
            ee2[buf] = e2g[code0 + (i + 2) * 16 + l15];
        }
        const f32x4 z = {0.0f, 0.0f, 0.0f, 0.0f};
#pragma unroll
        for (int rt = 0; rt < 4; ++rt) {
            f32x4 acc = __builtin_amdgcn_mfma_f32_16x16x32_bf16(afrag[rt][0], B0, z, 0, 0, 0);
            acc = __builtin_amdgcn_mfma_f32_16x16x32_bf16(afrag[rt][1], B1, acc, 0, 0, 0);
#pragma unroll
            for (int reg = 0; reg < 4; ++reg)
                runmin[rt][reg] = fminf(runmin[rt][reg], fmaf(-2.0f, acc[reg], e2v));
        }
    }

    // cross-lane min over the 16 l15 lanes sharing each row, then LDS combine of splits
#pragma unroll
    for (int rt = 0; rt < 4; ++rt)
#pragma unroll
        for (int reg = 0; reg < 4; ++reg) {
            float v = runmin[rt][reg];
            v = fminf(v, __shfl_xor(v, 1, 64));
            v = fminf(v, __shfl_xor(v, 2, 64));
            v = fminf(v, __shfl_xor(v, 4, 64));
            v = fminf(v, __shfl_xor(v, 8, 64));
            if (l15 == 0) sm[split * 64 + rt * 16 + quad * 4 + reg] = v;
        }
    __syncthreads();

    // global threshold per row: min over splits + rigorous bf16 margin
    // 2|d_np - d_bf| <= 2*2^-8*1.002*||x||*||e||max ~= 0.00785*sqrt(x2*e2max); use 0.01 + 0.02
    const float e2max = __int_as_float(*e2max_bits);
    float thr[4][4];
#pragma unroll
    for (int rt = 0; rt < 4; ++rt)
#pragma unroll
        for (int reg = 0; reg < 4; ++reg) {
            int rl = rt * 16 + quad * 4 + reg;
            float gm = fminf(fminf(sm[rl], sm[64 + rl]), fminf(sm[128 + rl], sm[192 + rl]));
            float xv = x2g[row0 + rl];
            thr[rt][reg] = gm + 0.01f * sqrtf(xv * e2max) + 0.02f;
        }

    // ---------- Pass B: collect against fixed global threshold ----------
#pragma unroll
    for (int i = 0; i < 2; ++i) {
        const uint4* p = Qb + i * 128 + lane;
        bb0[i] = *(const bf16x8*)p;
        bb1[i] = *(const bf16x8*)(p + 64);
        ee2[i] = e2g[code0 + i * 16 + l15];
    }
#pragma unroll 2
    for (int i = 0; i < 128; ++i) {
        const int buf = i & 1;
        const bf16x8 B0 = bb0[buf];
        const bf16x8 B1 = bb1[buf];
        const float e2v = ee2[buf];
        if (i < 126) {
            const uint4* p = Qb + (i + 2) * 128 + lane;
            bb0[buf] = *(const bf16x8*)p;
            bb1[buf] = *(const bf16x8*)(p + 64);
            ee2[buf] = e2g[code0 + (i + 2) * 16 + l15];
        }
        const int myCode = code0 + i * 16 + l15;
        const f32x4 z = {0.0f, 0.0f, 0.0f, 0.0f};
#pragma unroll
        for (int rt = 0; rt < 4; ++rt) {
            f32x4 acc = __builtin_amdgcn_mfma_f32_16x16x32_bf16(afrag[rt][0], B0, z, 0, 0, 0);
            acc = __builtin_amdgcn_mfma_f32_16x16x32_bf16(afrag[rt][1], B1, acc, 0, 0, 0);
#pragma unroll
            for (int reg = 0; reg < 4; ++reg) {
                float sc = fmaf(-2.0f, acc[reg], e2v);
                if (sc <= thr[rt][reg]) {  // rare (~1-2 codes/row over all of K)
                    int row = row0 + rt * 16 + quad * 4 + reg;
                    int pos = atomicAdd(&cnt[row], 1);
                    if (pos < CAP) slots[(size_t)row * CAP + pos] = myCode;
                }
            }
        }
    }
}

// finalize: exact fp32 re-evaluation of candidates (numpy-order), outputs
__global__ __launch_bounds__(256) void finalize2_kernel(const float* __restrict__ x,
                                                        const float* __restrict__ cb,
                                                        const float* __restrict__ x2,
                                                        const float* __restrict__ e2,
                                                        const int* __restrict__ cnt,
                                                        const int* __restrict__ slots,
                                                        float* __restrict__ out) {
    __shared__ float bvs[256];
    __shared__ int bis[256];
    int t = blockIdx.x * 256 + threadIdx.x;  // N_ROWS*4 threads
    int r = t >> 2, j = t & 3;
    const int tid = threadIdx.x;

    float xr[64];
#pragma unroll
    for (int q = 0; q < 16; ++q) {
        float4 v = ((const float4*)(x + (size_t)r * DDIM))[q];
        xr[q * 4 + 0] = v.x; xr[q * 4 + 1] = v.y; xr[q * 4 + 2] = v.z; xr[q * 4 + 3] = v.w;
    }
    float x2v = x2[r];

    float bv = 3.0e38f;
    int bi = 0x7fffffff;
    int c = cnt[r];
    if (c > 0 && c <= CAP) {
        for (int i = j; i < c; i += 4) {
            int code = slots[(size_t)r * CAP + i];
            float xe = 0.0f;
            const float4* e4 = (const float4*)(cb + (size_t)code * DDIM);
#pragma unroll
            for (int q = 0; q < 16; ++q) {
                float4 ev = e4[q];
                xe = fmaf(xr[q * 4 + 0], ev.x, xe);
                xe = fmaf(xr[q * 4 + 1], ev.y, xe);
                xe = fmaf(xr[q * 4 + 2], ev.z, xe);
                xe = fmaf(xr[q * 4 + 3], ev.w, xe);
            }
            float ts = x2v + e2[code];
            float dist = fmaf(-2.0f, xe, ts);
            if (dist < bv || (dist == bv && code < bi)) { bv = dist; bi = code; }
        }
    } else {
        // backstop: full scan (covers c==0 / overflow; should never trigger)
        for (int code = j; code < KCODES; code += 4) {
            float xe = 0.0f;
            const float4* e4 = (const float4*)(cb + (size_t)code * DDIM);
#pragma unroll
            for (int q = 0; q < 16; ++q) {
                float4 ev = e4[q];
                xe = fmaf(xr[q * 4 + 0], ev.x, xe);
                xe = fmaf(xr[q * 4 + 1], ev.y, xe);
                xe = fmaf(xr[q * 4 + 2], ev.z, xe);
                xe = fmaf(xr[q * 4 + 3], ev.w, xe);
            }
            float ts = x2v + e2[code];
            float dist = fmaf(-2.0f, xe, ts);
            if (dist < bv || (dist == bv && code < bi)) { bv = dist; bi = code; }
        }
    }
    bvs[tid] = bv;
    bis[tid] = bi;
    __syncthreads();
    int base = tid & ~3;
    if (j == 0) {
#pragma unroll
        for (int jj = 1; jj < 4; ++jj) {
            float v = bvs[base + jj];
            int ii = bis[base + jj];
            if (v < bv || (v == bv && ii < bi)) { bv = v; bi = ii; }
        }
        bis[base] = bi;
    }
    __syncthreads();
    int best = bis[base];

    const float4* qs = (const float4*)(cb + (size_t)best * DDIM);
    float4* os = (float4*)(out + (size_t)r * DDIM);
#pragma unroll
    for (int i = 0; i < 4; ++i) {
        float4 qv = qs[j * 4 + i];
        float xv0 = xr[(j * 4 + i) * 4 + 0], xv1 = xr[(j * 4 + i) * 4 + 1];
        float xv2 = xr[(j * 4 + i) * 4 + 2], xv3 = xr[(j * 4 + i) * 4 + 3];
        float4 ov;
        ov.x = xv0 + (qv.x - xv0);
        ov.y = xv1 + (qv.y - xv1);
        ov.z = xv2 + (qv.z - xv2);
        ov.w = xv3 + (qv.w - xv3);
        os[j * 4 + i] = ov;
    }
    if (j == 0) out[(size_t)N_ROWS * DDIM + r] = (float)best;
}

// ===================== FALLBACK PATH (round-1, correct at 493 us) =====================
#define SPLITK 4
#define KPER (KCODES / SPLITK)
#define TM 128
#define TKT 128
#define NTILES (KPER / TKT)
#define LDSX 132
#define LDSE 132

__global__ __launch_bounds__(256) void sumsq_kernel(const float* __restrict__ x,
                                                    const float* __restrict__ cb,
                                                    float* __restrict__ ws) {
#pragma clang fp contract(off)
    int t = blockIdx.x * 256 + threadIdx.x;
    const float* src;
    float* dst;
    if (t < KCODES) { src = cb + (size_t)t * DDIM; dst = ws + t; }
    else { int r = t - KCODES; src = x + (size_t)r * DDIM; dst = ws + KCODES + r; }
    float acc[8];
#pragma unroll
    for (int j = 0; j < 8; ++j) { float v = src[j]; acc[j] = v * v; }
#pragma unroll
    for (int i = 8; i < 64; i += 8)
#pragma unroll
        for (int j = 0; j < 8; ++j) { float v = src[i + j]; acc[j] = acc[j] + v * v; }
    *dst = ((acc[0] + acc[1]) + (acc[2] + acc[3])) + ((acc[4] + acc[5]) + (acc[6] + acc[7]));
}

__global__ __launch_bounds__(256) void dist_argmin_kernel(const float* __restrict__ x,
                                                          const float* __restrict__ cb,
                                                          const float* __restrict__ e2g,
                                                          const float* __restrict__ x2g,
                                                          float2* __restrict__ partial) {
    __shared__ float smem[DDIM * LDSX + DDIM * LDSE];
    float* Xs = smem;
    float* Es = smem + DDIM * LDSX;
    const int tid = threadIdx.x;
    const int row0 = blockIdx.x * TM;
    const int code0 = blockIdx.y * KPER;
    const int tr = tid >> 4, tc = tid & 15;
    for (int i = tid; i < TM * 16; i += 256) {
        int r = i >> 4, q = i & 15;
        float4 v = ((const float4*)(x + (size_t)(row0 + r) * DDIM))[q];
        Xs[(4 * q + 0) * LDSX + r] = v.x; Xs[(4 * q + 1) * LDSX + r] = v.y;
        Xs[(4 * q + 2) * LDSX + r] = v.z; Xs[(4 * q + 3) * LDSX + r] = v.w;
    }
    float x2v[8];
#pragma unroll
    for (int j = 0; j < 8; ++j) x2v[j] = x2g[row0 + tr * 8 + j];
    float bestV[8]; int bestI[8];
#pragma unroll
    for (int j = 0; j < 8; ++j) { bestV[j] = 3.0e38f; bestI[j] = 0; }
    for (int t = 0; t < NTILES; ++t) {
        __syncthreads();
        const int cbase = code0 + t * TKT;
        for (int i = tid; i < TKT * 16; i += 256) {
            int c = i >> 4, q = i & 15;
            float4 v = ((const float4*)(cb + (size_t)(cbase + c) * DDIM))[q];
            Es[(4 * q + 0) * LDSE + c] = v.x; Es[(4 * q + 1) * LDSE + c] = v.y;
            Es[(4 * q + 2) * LDSE + c] = v.z; Es[(4 * q + 3) * LDSE + c] = v.w;
        }
        __syncthreads();
        float acc[8][8];
#pragma unroll
        for (int a = 0; a < 8; ++a)
#pragma unroll
            for (int b = 0; b < 8; ++b) acc[a][b] = 0.0f;
#pragma unroll 4
        for (int d = 0; d < DDIM; ++d) {
            float xv[8], ev[8];
            float4 xa = *(const float4*)&Xs[d * LDSX + tr * 8];
            float4 xb = *(const float4*)&Xs[d * LDSX + tr * 8 + 4];
            float4 ea = *(const float4*)&Es[d * LDSE + tc * 8];
            float4 eb = *(const float4*)&Es[d * LDSE + tc * 8 + 4];
            xv[0] = xa.x; xv[1] = xa.y; xv[2] = xa.z; xv[3] = xa.w;
            xv[4] = xb.x; xv[5] = xb.y; xv[6] = xb.z; xv[7] = xb.w;
            ev[0] = ea.x; ev[1] = ea.y; ev[2] = ea.z; ev[3] = ea.w;
            ev[4] = eb.x; ev[5] = eb.y; ev[6] = eb.z; ev[7] = eb.w;
#pragma unroll
            for (int a = 0; a < 8; ++a)
#pragma unroll
                for (int b = 0; b < 8; ++b) acc[a][b] = fmaf(xv[a], ev[b], acc[a][b]);
        }
#pragma unroll
        for (int b = 0; b < 8; ++b) {
            int ci = cbase + tc * 8 + b;
            float e2 = e2g[ci];
#pragma unroll
            for (int a = 0; a < 8; ++a) {
                float ts = x2v[a] + e2;
                float dist = fmaf(-2.0f, acc[a][b], ts);
                if (dist < bestV[a]) { bestV[a] = dist; bestI[a] = ci; }
            }
        }
    }
    __syncthreads();
    float* redV = Es;
    int* redI = (int*)(Es + TM * 16);
#pragma unroll
    for (int a = 0; a < 8; ++a) {
        redV[(tr * 8 + a) * 16 + tc] = bestV[a];
        redI[(tr * 8 + a) * 16 + tc] = bestI[a];
    }
    __syncthreads();
    if (tid < TM) {
        float bv = redV[tid * 16];
        int bi = redI[tid * 16];
#pragma unroll
        for (int c = 1; c < 16; ++c) {
            float v = redV[tid * 16 + c];
            int ii = redI[tid * 16 + c];
            if (v < bv || (v == bv && ii < bi)) { bv = v; bi = ii; }
        }
        partial[(size_t)(row0 + tid) * SPLITK + blockIdx.y] = make_float2(bv, __int_as_float(bi));
    }
}

__global__ __launch_bounds__(256) void finalize_kernel(const float2* __restrict__ partial,
                                                       const float* __restrict__ x,
                                                       const float* __restrict__ cb,
                                                       float* __restrict__ out) {
    int t = blockIdx.x * 256 + threadIdx.x;
    int r = t >> 2, j = t & 3;
    float2 p = partial[(size_t)r * SPLITK];
    float bv = p.x;
    int bi = __float_as_int(p.y);
#pragma unroll
    for (int k = 1; k < SPLITK; ++k) {
        float2 q = partial[(size_t)r * SPLITK + k];
        int qi = __float_as_int(q.y);
        if (q.x < bv || (q.x == bv && qi < bi)) { bv = q.x; bi = qi; }
    }
    const float4* xs = (const float4*)(x + (size_t)r * DDIM);
    const float4* qs = (const float4*)(cb + (size_t)bi * DDIM);
    float4* os = (float4*)(out + (size_t)r * DDIM);
#pragma unroll
    for (int i = 0; i < 4; ++i) {
        float4 xv = xs[j * 4 + i];
        float4 qv = qs[j * 4 + i];
        float4 ov;
        ov.x = xv.x + (qv.x - xv.x); ov.y = xv.y + (qv.y - xv.y);
        ov.z = xv.z + (qv.z - xv.z); ov.w = xv.w + (qv.w - xv.w);
        os[j * 4 + i] = ov;
    }
    if (j == 0) out[(size_t)N_ROWS * DDIM + r] = (float)bi;
}

// ===================== LAUNCH =====================
extern "C" void kernel_launch(void* const* d_in, const int* in_sizes, int n_in,
                              void* d_out, int out_size, void* d_ws, size_t ws_size,
                              hipStream_t stream) {
    const float* x = (const float*)d_in[0];
    const float* cb = (const float*)d_in[1];
    float* out = (float*)d_out;

    if (ws_size >= WS_NEEDED) {
        unsigned char* ws = (unsigned char*)d_ws;
        unsigned short* xbf = (unsigned short*)(ws + O_XBF);
        uint4* qperm = (uint4*)(ws + O_QPERM);
        float* x2 = (float*)(ws + O_X2);
        float* e2 = (float*)(ws + O_E2);
        int* e2max_bits = (int*)(ws + O_E2MAX);
        int* cnt = (int*)(ws + O_CNT);
        int* slots = (int*)(ws + O_SLOTS);

        prep_kernel<<<(N_ROWS + KCODES) / 256, 256, 0, stream>>>(x, cb, xbf, qperm, x2, e2,
                                                                 e2max_bits, cnt);
        screen_kernel<<<N_ROWS / 64, 256, 0, stream>>>(xbf, qperm, x2, e2, e2max_bits, cnt,
                                                       slots);
        finalize2_kernel<<<(N_ROWS * 4) / 256, 256, 0, stream>>>(x, cb, x2, e2, cnt, slots, out);
    } else {
        float* ws = (float*)d_ws;
        float* e2 = ws;
        float* x2 = ws + KCODES;
        float2* partial = (float2*)(ws + KCODES + N_ROWS);
        sumsq_kernel<<<(KCODES + N_ROWS) / 256, 256, 0, stream>>>(x, cb, ws);
        dim3 grid(N_ROWS / TM, SPLITK);
        dist_argmin_kernel<<<grid, 256, 0, stream>>>(x, cb, e2, x2, partial);
        finalize_kernel<<<(N_ROWS * 4) / 256, 256, 0, stream>>>(partial, x, cb, out);
    }
}

// Round 5
// 211.245 us; speedup vs baseline: 14.9628x; 1.0431x over previous
//
#include <hip/hip_runtime.h>
#include <hip/hip_bf16.h>
#include <math.h>

// Problem constants (B=16, T=2048, D=64, K=8192)
#define N_ROWS 32768
#define KCODES 8192
#define DDIM 64

typedef __attribute__((ext_vector_type(8))) short bf16x8;
typedef __attribute__((ext_vector_type(4))) float f32x4;

// ===================== FAST PATH =====================
// ws layout (bytes):
//   O_XBF   = 0        : x_bf   N*64 bf16            (4 MB)
//   O_QPERM = 4 MB     : codebook in MFMA-B-frag order (1 MB)
//   O_X2    = 5242880  : x2  N f32
//   O_E2    = 5373952  : e2  K f32
//   O_E2MAX = 5406720  : 1 f32 (atomicMax int-bits)
//   O_CNT   = 5406736  : per-row candidate counts, N i32
//   O_GMIN  = 5537808  : per-row global bf16-score min, N u32 (order-preserving key)
//   O_SLOTS = 5668880  : candidates N*CAP i32 (2 MB)
#define CAP 16
#define O_XBF   0
#define O_QPERM 4194304UL
#define O_X2    5242880UL
#define O_E2    5373952UL
#define O_E2MAX 5406720UL
#define O_CNT   5406736UL
#define O_GMIN  5537808UL
#define O_SLOTS 5668880UL
#define WS_NEEDED (O_SLOTS + (size_t)N_ROWS * CAP * 4)

__device__ __forceinline__ unsigned short f2bf(float f) {
    __hip_bfloat16 h = __float2bfloat16(f);  // RNE
    union { __hip_bfloat16 b; unsigned short u; } u;
    u.b = h;
    return u.u;
}

// order-preserving float<->uint key (ascending float -> ascending uint)
__device__ __forceinline__ unsigned int fkey(float f) {
    unsigned int b = __float_as_uint(f);
    return (b & 0x80000000u) ? ~b : (b | 0x80000000u);
}
__device__ __forceinline__ float funkey(unsigned int k) {
    unsigned int b = (k & 0x80000000u) ? (k & 0x7FFFFFFFu) : ~k;
    return __uint_as_float(b);
}

// prep: bf16 convert (x -> xbf rows; cb -> Qperm fragment-order) + numpy-pairwise
// sumsq + e2max (wave-reduced) + init counters/gmin
__global__ __launch_bounds__(256) void prep_kernel(const float* __restrict__ x,
                                                   const float* __restrict__ cb,
                                                   unsigned short* __restrict__ xbf,
                                                   uint4* __restrict__ qperm,
                                                   float* __restrict__ x2,
                                                   float* __restrict__ e2,
                                                   int* __restrict__ e2max_bits,
                                                   int* __restrict__ cnt,
                                                   unsigned int* __restrict__ gmin) {
#pragma clang fp contract(off)
    int t = blockIdx.x * 256 + threadIdx.x;  // exactly N_ROWS + KCODES threads
    bool iscb = (t >= N_ROWS);
    int r = iscb ? (t - N_ROWS) : t;
    const float* src = iscb ? (cb + (size_t)r * DDIM) : (x + (size_t)r * DDIM);
    if (!iscb) {
        cnt[r] = 0;
        gmin[r] = 0xFFFFFFFFu;  // +inf key
    }

    // build bf16 row as 8 x 16B chunks
    uint4 ch[8];
#pragma unroll
    for (int h = 0; h < 8; ++h) {
        float4 v0 = ((const float4*)src)[h * 2];
        float4 v1 = ((const float4*)src)[h * 2 + 1];
        ushort4 a, b;
        a.x = f2bf(v0.x); a.y = f2bf(v0.y); a.z = f2bf(v0.z); a.w = f2bf(v0.w);
        b.x = f2bf(v1.x); b.y = f2bf(v1.y); b.z = f2bf(v1.z); b.w = f2bf(v1.w);
        union { struct { ushort4 lo, hi; } s; uint4 u; } pk;
        pk.s.lo = a; pk.s.hi = b;
        ch[h] = pk.u;
    }
    if (!iscb) {
        uint4* dst = (uint4*)(xbf + (size_t)r * DDIM);
#pragma unroll
        for (int h = 0; h < 8; ++h) dst[h] = ch[h];
    } else {
        // frag-order: slot = ((c>>4)*2 + (h>>2))*64 + (h&3)*16 + (c&15)
        int g = r >> 4, l15 = r & 15;
#pragma unroll
        for (int h = 0; h < 8; ++h) {
            int slot = (g * 2 + (h >> 2)) * 64 + (h & 3) * 16 + l15;
            qperm[slot] = ch[h];
        }
    }

    // numpy pairwise sumsq (8 accumulators, contraction off)
    float acc[8];
#pragma unroll
    for (int j = 0; j < 8; ++j) { float v = src[j]; acc[j] = v * v; }
#pragma unroll
    for (int i = 8; i < 64; i += 8)
#pragma unroll
        for (int j = 0; j < 8; ++j) { float v = src[i + j]; acc[j] = acc[j] + v * v; }
    float s = ((acc[0] + acc[1]) + (acc[2] + acc[3])) + ((acc[4] + acc[5]) + (acc[6] + acc[7]));
    if (!iscb) {
        x2[r] = s;
    } else {
        e2[r] = s;
        // wave-level max, then one atomic per wave (blocks are pure-cb: N_ROWS%256==0)
        float wm = s;
#pragma unroll
        for (int m = 1; m < 64; m <<= 1) wm = fmaxf(wm, __shfl_xor(wm, m, 64));
        if ((threadIdx.x & 63) == 0) atomicMax(e2max_bits, __float_as_int(wm));
    }
}

// ---- screen phase 1: bf16 MFMA min-only (no branches), per-row global min via atomicMin ----
// grid (512, 4) x 256 thr: block = 64 rows x 2048 codes; wave w = 512-code chunk (32 tiles).
__global__ __launch_bounds__(256) void screen_min_kernel(const unsigned short* __restrict__ xbf,
                                                         const uint4* __restrict__ qperm,
                                                         const float* __restrict__ e2g,
                                                         unsigned int* __restrict__ gmin) {
    const int tid = threadIdx.x;
    const int w = tid >> 6;
    const int lane = tid & 63;
    const int l15 = lane & 15;
    const int quad = lane >> 4;
    const int row0 = blockIdx.x * 64;
    const int T0 = blockIdx.y * 128 + w * 32;  // global 16-code tile index

    bf16x8 afrag[4][2];
#pragma unroll
    for (int rt = 0; rt < 4; ++rt)
#pragma unroll
        for (int s = 0; s < 2; ++s)
            afrag[rt][s] = *(const bf16x8*)(xbf + (size_t)(row0 + rt * 16 + l15) * DDIM +
                                            s * 32 + quad * 8);

    bf16x8 bb0[2], bb1[2];
    float ee2[2];
#pragma unroll
    for (int i = 0; i < 2; ++i) {
        const uint4* p = qperm + (size_t)(T0 + i) * 128 + lane;
        bb0[i] = *(const bf16x8*)p;
        bb1[i] = *(const bf16x8*)(p + 64);
        ee2[i] = e2g[(T0 + i) * 16 + l15];
    }

    float runmin[4][4];
#pragma unroll
    for (int rt = 0; rt < 4; ++rt)
#pragma unroll
        for (int reg = 0; reg < 4; ++reg) runmin[rt][reg] = 3.0e38f;

#pragma unroll 2
    for (int i = 0; i < 32; ++i) {
        const int buf = i & 1;
        const bf16x8 B0 = bb0[buf];
        const bf16x8 B1 = bb1[buf];
        const float e2v = ee2[buf];
        if (i < 30) {
            const uint4* p = qperm + (size_t)(T0 + i + 2) * 128 + lane;
            bb0[buf] = *(const bf16x8*)p;
            bb1[buf] = *(const bf16x8*)(p + 64);
            ee2[buf] = e2g[(T0 + i + 2) * 16 + l15];
        }
        const f32x4 z = {0.0f, 0.0f, 0.0f, 0.0f};
#pragma unroll
        for (int rt = 0; rt < 4; ++rt) {
            f32x4 acc = __builtin_amdgcn_mfma_f32_16x16x32_bf16(afrag[rt][0], B0, z, 0, 0, 0);
            acc = __builtin_amdgcn_mfma_f32_16x16x32_bf16(afrag[rt][1], B1, acc, 0, 0, 0);
#pragma unroll
            for (int reg = 0; reg < 4; ++reg)
                runmin[rt][reg] = fminf(runmin[rt][reg], fmaf(-2.0f, acc[reg], e2v));
        }
    }

    // cross-lane min over the 16 l15-lanes sharing each row; lane l15==0 commits
#pragma unroll
    for (int rt = 0; rt < 4; ++rt)
#pragma unroll
        for (int reg = 0; reg < 4; ++reg) {
            float v = runmin[rt][reg];
            v = fminf(v, __shfl_xor(v, 1, 64));
            v = fminf(v, __shfl_xor(v, 2, 64));
            v = fminf(v, __shfl_xor(v, 4, 64));
            v = fminf(v, __shfl_xor(v, 8, 64));
            if (l15 == 0) atomicMin(&gmin[row0 + rt * 16 + quad * 4 + reg], fkey(v));
        }
}

// ---- screen phase 2: collect codes with sc <= global_min + M (rare -> cheap atomics) ----
__global__ __launch_bounds__(256) void screen_collect_kernel(
    const unsigned short* __restrict__ xbf, const uint4* __restrict__ qperm,
    const float* __restrict__ x2g, const float* __restrict__ e2g,
    const int* __restrict__ e2max_bits, const unsigned int* __restrict__ gmin,
    int* __restrict__ cnt, int* __restrict__ slots) {
    const int tid = threadIdx.x;
    const int w = tid >> 6;
    const int lane = tid & 63;
    const int l15 = lane & 15;
    const int quad = lane >> 4;
    const int row0 = blockIdx.x * 64;
    const int T0 = blockIdx.y * 128 + w * 32;

    bf16x8 afrag[4][2];
#pragma unroll
    for (int rt = 0; rt < 4; ++rt)
#pragma unroll
        for (int s = 0; s < 2; ++s)
            afrag[rt][s] = *(const bf16x8*)(xbf + (size_t)(row0 + rt * 16 + l15) * DDIM +
                                            s * 32 + quad * 8);

    // per-element threshold: gm + rigorous bf16 margin (validated rounds 2/4, absmax 0)
    const float e2max = __int_as_float(*e2max_bits);
    float thr[4][4];
#pragma unroll
    for (int rt = 0; rt < 4; ++rt)
#pragma unroll
        for (int reg = 0; reg < 4; ++reg) {
            int row = row0 + rt * 16 + quad * 4 + reg;
            float gm = funkey(gmin[row]);
            thr[rt][reg] = gm + 0.01f * sqrtf(x2g[row] * e2max) + 0.02f;
        }

    bf16x8 bb0[2], bb1[2];
    float ee2[2];
#pragma unroll
    for (int i = 0; i < 2; ++i) {
        const uint4* p = qperm + (size_t)(T0 + i) * 128 + lane;
        bb0[i] = *(const bf16x8*)p;
        bb1[i] = *(const bf16x8*)(p + 64);
        ee2[i] = e2g[(T0 + i) * 16 + l15];
    }

#pragma unroll 2
    for (int i = 0; i < 32; ++i) {
        const int buf = i & 1;
        const bf16x8 B0 = bb0[buf];
        const bf16x8 B1 = bb1[buf];
        const float e2v = ee2[buf];
        if (i < 30) {
            const uint4* p = qperm + (size_t)(T0 + i + 2) * 128 + lane;
            bb0[buf] = *(const bf16x8*)p;
            bb1[buf] = *(const bf16x8*)(p + 64);
            ee2[buf] = e2g[(T0 + i + 2) * 16 + l15];
        }
        const int myCode = (T0 + i) * 16 + l15;
        const f32x4 z = {0.0f, 0.0f, 0.0f, 0.0f};
#pragma unroll
        for (int rt = 0; rt < 4; ++rt) {
            f32x4 acc = __builtin_amdgcn_mfma_f32_16x16x32_bf16(afrag[rt][0], B0, z, 0, 0, 0);
            acc = __builtin_amdgcn_mfma_f32_16x16x32_bf16(afrag[rt][1], B1, acc, 0, 0, 0);
#pragma unroll
            for (int reg = 0; reg < 4; ++reg) {
                float sc = fmaf(-2.0f, acc[reg], e2v);
                if (sc <= thr[rt][reg]) {  // ~1-2 codes/row over all K
                    int row = row0 + rt * 16 + quad * 4 + reg;
                    int pos = atomicAdd(&cnt[row], 1);
                    if (pos < CAP) slots[(size_t)row * CAP + pos] = myCode;
                }
            }
        }
    }
}

// finalize: exact fp32 re-evaluation of candidates (numpy-order), outputs
__global__ __launch_bounds__(256) void finalize2_kernel(const float* __restrict__ x,
                                                        const float* __restrict__ cb,
                                                        const float* __restrict__ x2,
                                                        const float* __restrict__ e2,
                                                        const int* __restrict__ cnt,
                                                        const int* __restrict__ slots,
                                                        float* __restrict__ out) {
    __shared__ float bvs[256];
    __shared__ int bis[256];
    int t = blockIdx.x * 256 + threadIdx.x;  // N_ROWS*4 threads
    int r = t >> 2, j = t & 3;
    const int tid = threadIdx.x;

    float xr[64];
#pragma unroll
    for (int q = 0; q < 16; ++q) {
        float4 v = ((const float4*)(x + (size_t)r * DDIM))[q];
        xr[q * 4 + 0] = v.x; xr[q * 4 + 1] = v.y; xr[q * 4 + 2] = v.z; xr[q * 4 + 3] = v.w;
    }
    float x2v = x2[r];

    float bv = 3.0e38f;
    int bi = 0x7fffffff;
    int c = cnt[r];
    if (c > 0 && c <= CAP) {
        for (int i = j; i < c; i += 4) {
            int code = slots[(size_t)r * CAP + i];
            float xe = 0.0f;
            const float4* e4 = (const float4*)(cb + (size_t)code * DDIM);
#pragma unroll
            for (int q = 0; q < 16; ++q) {
                float4 ev = e4[q];
                xe = fmaf(xr[q * 4 + 0], ev.x, xe);
                xe = fmaf(xr[q * 4 + 1], ev.y, xe);
                xe = fmaf(xr[q * 4 + 2], ev.z, xe);
                xe = fmaf(xr[q * 4 + 3], ev.w, xe);
            }
            float ts = x2v + e2[code];
            float dist = fmaf(-2.0f, xe, ts);
            if (dist < bv || (dist == bv && code < bi)) { bv = dist; bi = code; }
        }
    } else {
        // backstop: full scan (covers c==0 / overflow; should never trigger)
        for (int code = j; code < KCODES; code += 4) {
            float xe = 0.0f;
            const float4* e4 = (const float4*)(cb + (size_t)code * DDIM);
#pragma unroll
            for (int q = 0; q < 16; ++q) {
                float4 ev = e4[q];
                xe = fmaf(xr[q * 4 + 0], ev.x, xe);
                xe = fmaf(xr[q * 4 + 1], ev.y, xe);
                xe = fmaf(xr[q * 4 + 2], ev.z, xe);
                xe = fmaf(xr[q * 4 + 3], ev.w, xe);
            }
            float ts = x2v + e2[code];
            float dist = fmaf(-2.0f, xe, ts);
            if (dist < bv || (dist == bv && code < bi)) { bv = dist; bi = code; }
        }
    }
    bvs[tid] = bv;
    bis[tid] = bi;
    __syncthreads();
    int base = tid & ~3;
    if (j == 0) {
#pragma unroll
        for (int jj = 1; jj < 4; ++jj) {
            float v = bvs[base + jj];
            int ii = bis[base + jj];
            if (v < bv || (v == bv && ii < bi)) { bv = v; bi = ii; }
        }
        bis[base] = bi;
    }
    __syncthreads();
    int best = bis[base];

    const float4* qs = (const float4*)(cb + (size_t)best * DDIM);
    float4* os = (float4*)(out + (size_t)r * DDIM);
#pragma unroll
    for (int i = 0; i < 4; ++i) {
        float4 qv = qs[j * 4 + i];
        float xv0 = xr[(j * 4 + i) * 4 + 0], xv1 = xr[(j * 4 + i) * 4 + 1];
        float xv2 = xr[(j * 4 + i) * 4 + 2], xv3 = xr[(j * 4 + i) * 4 + 3];
        float4 ov;
        ov.x = xv0 + (qv.x - xv0);
        ov.y = xv1 + (qv.y - xv1);
        ov.z = xv2 + (qv.z - xv2);
        ov.w = xv3 + (qv.w - xv3);
        os[j * 4 + i] = ov;
    }
    if (j == 0) out[(size_t)N_ROWS * DDIM + r] = (float)best;
}

// ===================== FALLBACK PATH (round-1, correct at 493 us) =====================
#define SPLITK 4
#define KPER (KCODES / SPLITK)
#define TM 128
#define TKT 128
#define NTILES (KPER / TKT)
#define LDSX 132
#define LDSE 132

__global__ __launch_bounds__(256) void sumsq_kernel(const float* __restrict__ x,
                                                    const float* __restrict__ cb,
                                                    float* __restrict__ ws) {
#pragma clang fp contract(off)
    int t = blockIdx.x * 256 + threadIdx.x;
    const float* src;
    float* dst;
    if (t < KCODES) { src = cb + (size_t)t * DDIM; dst = ws + t; }
    else { int r = t - KCODES; src = x + (size_t)r * DDIM; dst = ws + KCODES + r; }
    float acc[8];
#pragma unroll
    for (int j = 0; j < 8; ++j) { float v = src[j]; acc[j] = v * v; }
#pragma unroll
    for (int i = 8; i < 64; i += 8)
#pragma unroll
        for (int j = 0; j < 8; ++j) { float v = src[i + j]; acc[j] = acc[j] + v * v; }
    *dst = ((acc[0] + acc[1]) + (acc[2] + acc[3])) + ((acc[4] + acc[5]) + (acc[6] + acc[7]));
}

__global__ __launch_bounds__(256) void dist_argmin_kernel(const float* __restrict__ x,
                                                          const float* __restrict__ cb,
                                                          const float* __restrict__ e2g,
                                                          const float* __restrict__ x2g,
                                                          float2* __restrict__ partial) {
    __shared__ float smem[DDIM * LDSX + DDIM * LDSE];
    float* Xs = smem;
    float* Es = smem + DDIM * LDSX;
    const int tid = threadIdx.x;
    const int row0 = blockIdx.x * TM;
    const int code0 = blockIdx.y * KPER;
    const int tr = tid >> 4, tc = tid & 15;
    for (int i = tid; i < TM * 16; i += 256) {
        int r = i >> 4, q = i & 15;
        float4 v = ((const float4*)(x + (size_t)(row0 + r) * DDIM))[q];
        Xs[(4 * q + 0) * LDSX + r] = v.x; Xs[(4 * q + 1) * LDSX + r] = v.y;
        Xs[(4 * q + 2) * LDSX + r] = v.z; Xs[(4 * q + 3) * LDSX + r] = v.w;
    }
    float x2v[8];
#pragma unroll
    for (int j = 0; j < 8; ++j) x2v[j] = x2g[row0 + tr * 8 + j];
    float bestV[8]; int bestI[8];
#pragma unroll
    for (int j = 0; j < 8; ++j) { bestV[j] = 3.0e38f; bestI[j] = 0; }
    for (int t = 0; t < NTILES; ++t) {
        __syncthreads();
        const int cbase = code0 + t * TKT;
        for (int i = tid; i < TKT * 16; i += 256) {
            int c = i >> 4, q = i & 15;
            float4 v = ((const float4*)(cb + (size_t)(cbase + c) * DDIM))[q];
            Es[(4 * q + 0) * LDSE + c] = v.x; Es[(4 * q + 1) * LDSE + c] = v.y;
            Es[(4 * q + 2) * LDSE + c] = v.z; Es[(4 * q + 3) * LDSE + c] = v.w;
        }
        __syncthreads();
        float acc[8][8];
#pragma unroll
        for (int a = 0; a < 8; ++a)
#pragma unroll
            for (int b = 0; b < 8; ++b) acc[a][b] = 0.0f;
#pragma unroll 4
        for (int d = 0; d < DDIM; ++d) {
            float xv[8], ev[8];
            float4 xa = *(const float4*)&Xs[d * LDSX + tr * 8];
            float4 xb = *(const float4*)&Xs[d * LDSX + tr * 8 + 4];
            float4 ea = *(const float4*)&Es[d * LDSE + tc * 8];
            float4 eb = *(const float4*)&Es[d * LDSE + tc * 8 + 4];
            xv[0] = xa.x; xv[1] = xa.y; xv[2] = xa.z; xv[3] = xa.w;
            xv[4] = xb.x; xv[5] = xb.y; xv[6] = xb.z; xv[7] = xb.w;
            ev[0] = ea.x; ev[1] = ea.y; ev[2] = ea.z; ev[3] = ea.w;
            ev[4] = eb.x; ev[5] = eb.y; ev[6] = eb.z; ev[7] = eb.w;
#pragma unroll
            for (int a = 0; a < 8; ++a)
#pragma unroll
                for (int b = 0; b < 8; ++b) acc[a][b] = fmaf(xv[a], ev[b], acc[a][b]);
        }
#pragma unroll
        for (int b = 0; b < 8; ++b) {
            int ci = cbase + tc * 8 + b;
            float e2 = e2g[ci];
#pragma unroll
            for (int a = 0; a < 8; ++a) {
                float ts = x2v[a] + e2;
                float dist = fmaf(-2.0f, acc[a][b], ts);
                if (dist < bestV[a]) { bestV[a] = dist; bestI[a] = ci; }
            }
        }
    }
    __syncthreads();
    float* redV = Es;
    int* redI = (int*)(Es + TM * 16);
#pragma unroll
    for (int a = 0; a < 8; ++a) {
        redV[(tr * 8 + a) * 16 + tc] = bestV[a];
        redI[(tr * 8 + a) * 16 + tc] = bestI[a];
    }
    __syncthreads();
    if (tid < TM) {
        float bv = redV[tid * 16];
        int bi = redI[tid * 16];
#pragma unroll
        for (int c = 1; c < 16; ++c) {
            float v = redV[tid * 16 + c];
            int ii = redI[tid * 16 + c];
            if (v < bv || (v == bv && ii < bi)) { bv = v; bi = ii; }
        }
        partial[(size_t)(row0 + tid) * SPLITK + blockIdx.y] = make_float2(bv, __int_as_float(bi));
    }
}

__global__ __launch_bounds__(256) void finalize_kernel(const float2* __restrict__ partial,
                                                       const float* __restrict__ x,
                                                       const float* __restrict__ cb,
                                                       float* __restrict__ out) {
    int t = blockIdx.x * 256 + threadIdx.x;
    int r = t >> 2, j = t & 3;
    float2 p = partial[(size_t)r * SPLITK];
    float bv = p.x;
    int bi = __float_as_int(p.y);
#pragma unroll
    for (int k = 1; k < SPLITK; ++k) {
        float2 q = partial[(size_t)r * SPLITK + k];
        int qi = __float_as_int(q.y);
        if (q.x < bv || (q.x == bv && qi < bi)) { bv = q.x; bi = qi; }
    }
    const float4* xs = (const float4*)(x + (size_t)r * DDIM);
    const float4* qs = (const float4*)(cb + (size_t)bi * DDIM);
    float4* os = (float4*)(out + (size_t)r * DDIM);
#pragma unroll
    for (int i = 0; i < 4; ++i) {
        float4 xv = xs[j * 4 + i];
        float4 qv = qs[j * 4 + i];
        float4 ov;
        ov.x = xv.x + (qv.x - xv.x); ov.y = xv.y + (qv.y - xv.y);
        ov.z = xv.z + (qv.z - xv.z); ov.w = xv.w + (qv.w - xv.w);
        os[j * 4 + i] = ov;
    }
    if (j == 0) out[(size_t)N_ROWS * DDIM + r] = (float)bi;
}

// ===================== LAUNCH =====================
extern "C" void kernel_launch(void* const* d_in, const int* in_sizes, int n_in,
                              void* d_out, int out_size, void* d_ws, size_t ws_size,
                              hipStream_t stream) {
    const float* x = (const float*)d_in[0];
    const float* cb = (const float*)d_in[1];
    float* out = (float*)d_out;

    if (ws_size >= WS_NEEDED) {
        unsigned char* ws = (unsigned char*)d_ws;
        unsigned short* xbf = (unsigned short*)(ws + O_XBF);
        uint4* qperm = (uint4*)(ws + O_QPERM);
        float* x2 = (float*)(ws + O_X2);
        float* e2 = (float*)(ws + O_E2);
        int* e2max_bits = (int*)(ws + O_E2MAX);
        int* cnt = (int*)(ws + O_CNT);
        unsigned int* gmin = (unsigned int*)(ws + O_GMIN);
        int* slots = (int*)(ws + O_SLOTS);

        prep_kernel<<<(N_ROWS + KCODES) / 256, 256, 0, stream>>>(x, cb, xbf, qperm, x2, e2,
                                                                 e2max_bits, cnt, gmin);
        dim3 sg(N_ROWS / 64, 4);
        screen_min_kernel<<<sg, 256, 0, stream>>>(xbf, qperm, e2, gmin);
        screen_collect_kernel<<<sg, 256, 0, stream>>>(xbf, qperm, x2, e2, e2max_bits, gmin,
                                                      cnt, slots);
        finalize2_kernel<<<(N_ROWS * 4) / 256, 256, 0, stream>>>(x, cb, x2, e2, cnt, slots, out);
    } else {
        float* ws = (float*)d_ws;
        float* e2 = ws;
        float* x2 = ws + KCODES;
        float2* partial = (float2*)(ws + KCODES + N_ROWS);
        sumsq_kernel<<<(KCODES + N_ROWS) / 256, 256, 0, stream>>>(x, cb, ws);
        dim3 grid(N_ROWS / TM, SPLITK);
        dist_argmin_kernel<<<grid, 256, 0, stream>>>(x, cb, e2, x2, partial);
        finalize_kernel<<<(N_ROWS * 4) / 256, 256, 0, stream>>>(partial, x, cb, out);
    }
}